// Round 11
// baseline (185.357 us; speedup 1.0000x reference)
//
#include <hip/hip_runtime.h>
#include <hip/hip_bf16.h>
#include <stdint.h>

typedef __bf16  bf16x8 __attribute__((ext_vector_type(8)));
typedef __bf16  bf16x4 __attribute__((ext_vector_type(4)));
typedef float   f32x4  __attribute__((ext_vector_type(4)));
typedef uint32_t u32x4 __attribute__((ext_vector_type(4)));

#define SLEN  2048
#define DHEAD 128
#define QBLK  64            // 4 waves x 16 q-rows
#define KVBLK 32
#define NQT   (SLEN / QBLK) // 32
#define THR2  11.5415603f   // 8 * log2(e): defer-max threshold in exp2 domain

__device__ __forceinline__ uint32_t cvt_pk(float lo, float hi2) {
    uint32_t u;
    asm("v_cvt_pk_bf16_f32 %0, %1, %2" : "=v"(u) : "v"(lo), "v"(hi2));
    return u;
}

// native 2^x via builtin (compiler inserts the TRANS-op hazard waits)
__device__ __forceinline__ float exp2fast(float x) {
    return __builtin_amdgcn_exp2f(x);
}

__global__ __launch_bounds__(256, 4) void attn_fwd(
    const float* __restrict__ Q, const float* __restrict__ K,
    const float* __restrict__ V, float* __restrict__ O)
{
    const int bh = blockIdx.x;              // heads fastest
    const int qt = (NQT - 1) - blockIdx.y;  // LPT: longest first
    const int tid  = threadIdx.x;
    const int w    = tid >> 6;
    const int lane = tid & 63;
    const int r    = lane & 15;
    const int g    = lane >> 4;

    const size_t head_off = (size_t)bh * SLEN * DHEAD;
    const float* Qh = Q + head_off;
    const float* Kh = K + head_off;
    const float* Vh = V + head_off;
    float*       Oh = O + head_off;

    const int q0w = qt * QBLK + w * 16;     // wave's first q row

    __shared__ __bf16 K_sh [2][KVBLK * DHEAD];  // [32][256B], swz (row&15)<<4
    __shared__ __bf16 Vt_sh[2][DHEAD * 40];     // [128][80B], quad-xor swz

    // exp2-domain: fold log2(e) into the QK scale
    const float scale = 0.08838834764831845f * 1.4426950408889634f;

    // ---- Q fragments (B operand): col=q0w+r, k = kb*32 + g*8 + e ----
    bf16x8 qfrag[4];
    {
        const float4* qp = reinterpret_cast<const float4*>(
            Qh + (size_t)(q0w + r) * DHEAD + g * 8);
        #pragma unroll
        for (int kb = 0; kb < 4; ++kb) {
            float4 a = qp[kb*8 + 0];
            float4 b = qp[kb*8 + 1];
            a.x*=scale; a.y*=scale; a.z*=scale; a.w*=scale;
            b.x*=scale; b.y*=scale; b.z*=scale; b.w*=scale;
            bf16x8 f;
            f[0]=(__bf16)a.x; f[1]=(__bf16)a.y; f[2]=(__bf16)a.z; f[3]=(__bf16)a.w;
            f[4]=(__bf16)b.x; f[5]=(__bf16)b.y; f[6]=(__bf16)b.z; f[7]=(__bf16)b.w;
            qfrag[kb] = f;
        }
    }

    // staging regs
    float4 kreg[4], vreg[4];
    const int c4  = tid & 31;
    const int kvq = tid >> 5;        // 0..7: V kv-quad

    auto issue_loads = [&](int kv0) {
        #pragma unroll
        for (int it = 0; it < 4; ++it) {
            const int row = (it * 256 + tid) >> 5;
            kreg[it] = *reinterpret_cast<const float4*>(
                Kh + (size_t)(kv0 + row) * DHEAD + c4 * 4);
        }
        #pragma unroll
        for (int kr = 0; kr < 4; ++kr)
            vreg[kr] = *reinterpret_cast<const float4*>(
                Vh + (size_t)(kv0 + kvq * 4 + kr) * DHEAD + c4 * 4);
    };

    auto write_tiles = [&](int buf) {
        char* Kb  = reinterpret_cast<char*>(K_sh[buf]);
        char* Vtb = reinterpret_cast<char*>(Vt_sh[buf]);
        #pragma unroll
        for (int it = 0; it < 4; ++it) {
            const int row = (it * 256 + tid) >> 5;
            bf16x4 k4;
            k4[0]=(__bf16)kreg[it].x; k4[1]=(__bf16)kreg[it].y;
            k4[2]=(__bf16)kreg[it].z; k4[3]=(__bf16)kreg[it].w;
            *reinterpret_cast<bf16x4*>(
                Kb + row * 256 + ((c4 * 8) ^ ((row & 15) << 4))) = k4;
        }
        #pragma unroll
        for (int j = 0; j < 4; ++j) {
            const int d = c4 * 4 + j;
            bf16x4 v4;
            #pragma unroll
            for (int kr = 0; kr < 4; ++kr)
                v4[kr] = (__bf16)((&vreg[kr].x)[j]);
            *reinterpret_cast<bf16x4*>(
                Vtb + d * 80 + ((kvq ^ ((d >> 2) & 6)) * 8)) = v4;
        }
    };

    const f32x4 vzero = {0.f, 0.f, 0.f, 0.f};
    f32x4 acc_o[8];
    #pragma unroll
    for (int i = 0; i < 8; ++i) acc_o[i] = vzero;
    float m_run = -1e30f, l_run = 0.f;

    const int blkmax = 2 * qt + 1;           // block's last tile index
    const int my_max = (q0w + 15) >> 5;      // wave's last tile index

    // ---- QK for tile t from K buffer kb_buf ----
    auto do_qk = [&](f32x4* st, int t, int kb_buf) {
        char* Kb = reinterpret_cast<char*>(K_sh[kb_buf]);
        const bool a1 = (t * KVBLK + 16 <= q0w + 15);
        __builtin_amdgcn_s_setprio(1);
        #pragma unroll
        for (int tt = 0; tt < 2; ++tt) {
            st[tt] = vzero;
            if (tt == 1 && !a1) break;
            const int row = tt * 16 + r;
            #pragma unroll
            for (int kb = 0; kb < 4; ++kb) {
                bf16x8 kf = *reinterpret_cast<const bf16x8*>(
                    Kb + row * 256 + ((kb*64 + g*16) ^ ((row & 15) << 4)));
                st[tt] = __builtin_amdgcn_mfma_f32_16x16x32_bf16(
                    kf, qfrag[kb], st[tt], 0, 0, 0);
            }
        }
        __builtin_amdgcn_s_setprio(0);
    };

    // prologue: stage tile 0, QK(0), stage tile 1
    issue_loads(0);
    write_tiles(0);
    __syncthreads();
    issue_loads(KVBLK);          // FIX (was issue_loads(1)): tile 1 = rows 32..63
    f32x4 stp[2];
    do_qk(stp, 0, 0);
    write_tiles(1);

    for (int i = 0; i <= blkmax; ++i) {
        __syncthreads();                     // tile i+1 buffers complete
        const bool stage_more = (i + 2 <= blkmax);
        if (stage_more) issue_loads((i + 2) * KVBLK);

        // ---- QK(i+1) from buf[(i+1)&1] (overlaps SM(i) below) ----
        f32x4 stn[2];
        const bool do_next = (i + 1 <= my_max);
        if (do_next) do_qk(stn, i + 1, (i + 1) & 1);

        if (i <= my_max) {
            const int kv0 = i * KVBLK;
            char* Vtb = reinterpret_cast<char*>(Vt_sh[i & 1]);
            const bool alive1 = (kv0 + 16 <= q0w + 15);

            // ---- mask + in-register online softmax (exp2 domain) ----
            const int q = q0w + r;
            float pmax = -1e30f;
            #pragma unroll
            for (int t = 0; t < 2; ++t) {
                if (t == 1 && !alive1) break;
                if (kv0 + t*16 + 15 > q0w) {
                    #pragma unroll
                    for (int j = 0; j < 4; ++j)
                        if (kv0 + t*16 + 4*g + j > q) stp[t][j] = -1e30f;
                }
                #pragma unroll
                for (int j = 0; j < 4; ++j) pmax = fmaxf(pmax, stp[t][j]);
            }
            pmax = fmaxf(pmax, __shfl_xor(pmax, 16));
            pmax = fmaxf(pmax, __shfl_xor(pmax, 32));

            if (__any(pmax > m_run + THR2)) {    // rare (defer-max)
                const float m_new = fmaxf(m_run, pmax);
                const float corr  = exp2fast(m_run - m_new);
                l_run *= corr; m_run = m_new;
                #pragma unroll
                for (int reg = 0; reg < 4; ++reg) {
                    const float cr = __shfl(corr, 4*g + reg);
                    #pragma unroll
                    for (int dt = 0; dt < 8; ++dt) acc_o[dt][reg] *= cr;
                }
            }

            float rowsum = 0.f;
            #pragma unroll
            for (int t = 0; t < 2; ++t) {
                if (t == 1 && !alive1) break;
                #pragma unroll
                for (int j = 0; j < 4; ++j) {
                    const float p = exp2fast(stp[t][j] - m_run);
                    stp[t][j] = p;
                    rowsum += p;
                }
            }
            rowsum += __shfl_xor(rowsum, 16);
            rowsum += __shfl_xor(rowsum, 32);
            l_run += rowsum;

            // ---- P redistribute to A-fragment (k = g*8 + e) ----
            const uint32_t p00 = cvt_pk(stp[0][0], stp[0][1]);
            const uint32_t p01 = cvt_pk(stp[0][2], stp[0][3]);
            const uint32_t p10 = alive1 ? cvt_pk(stp[1][0], stp[1][1]) : 0u;
            const uint32_t p11 = alive1 ? cvt_pk(stp[1][2], stp[1][3]) : 0u;
            const int sA = r + ((2 * (g & 1)) << 4);
            const int sB = r + ((2 * (g & 1) + 1) << 4);
            u32x4 words;
            {
                const uint32_t lo0 = (uint32_t)__shfl((int)p00, sA);
                const uint32_t hi0 = (uint32_t)__shfl((int)p10, sA);
                const uint32_t lo1 = (uint32_t)__shfl((int)p01, sA);
                const uint32_t hi1 = (uint32_t)__shfl((int)p11, sA);
                const uint32_t lo2 = (uint32_t)__shfl((int)p00, sB);
                const uint32_t hi2 = (uint32_t)__shfl((int)p10, sB);
                const uint32_t lo3 = (uint32_t)__shfl((int)p01, sB);
                const uint32_t hi3 = (uint32_t)__shfl((int)p11, sB);
                words[0] = (g & 2) ? hi0 : lo0;
                words[1] = (g & 2) ? hi1 : lo1;
                words[2] = (g & 2) ? hi2 : lo2;
                words[3] = (g & 2) ? hi3 : lo3;
            }
            const bf16x8 pa = __builtin_bit_cast(bf16x8, words);

            // ---- PV: B = Vt[d = dt*16 + r][kv = g*8 ..] ----
            __builtin_amdgcn_s_setprio(1);
            #pragma unroll
            for (int dt = 0; dt < 8; ++dt) {
                const int d = dt * 16 + r;
                bf16x8 vf = *reinterpret_cast<const bf16x8*>(
                    Vtb + d * 80 + (((2*g) ^ ((d >> 2) & 6)) * 8));
                acc_o[dt] = __builtin_amdgcn_mfma_f32_16x16x32_bf16(
                    pa, vf, acc_o[dt], 0, 0, 0);
            }
            __builtin_amdgcn_s_setprio(0);
        }

        __syncthreads();                 // all PV reads of buf[i&1] done
        if (stage_more) write_tiles(i & 1);   // tile i+2 -> buf[(i+2)&1]

        stp[0] = stn[0];
        stp[1] = stn[1];
    }

    // ---- epilogue: O[q0w + 4g + reg][dt*16 + r] = acc / l ----
    const float inv = 1.0f / l_run;
    #pragma unroll
    for (int reg = 0; reg < 4; ++reg) {
        const float iv = __shfl(inv, 4*g + reg);
        float* orow = Oh + (size_t)(q0w + 4*g + reg) * DHEAD + r;
        #pragma unroll
        for (int dt = 0; dt < 8; ++dt)
            orow[dt * 16] = acc_o[dt][reg] * iv;
    }
}

extern "C" void kernel_launch(void* const* d_in, const int* in_sizes, int n_in,
                              void* d_out, int out_size, void* d_ws, size_t ws_size,
                              hipStream_t stream) {
    const float* Q = (const float*)d_in[0];
    const float* K = (const float*)d_in[1];
    const float* V = (const float*)d_in[2];
    float* O = (float*)d_out;
    dim3 grid(32 /* B*H */, NQT);
    attn_fwd<<<grid, 256, 0, stream>>>(Q, K, V, O);
}

// Round 12
// 91.862 us; speedup vs baseline: 2.0178x; 2.0178x over previous
//
#include <hip/hip_runtime.h>
#include <hip/hip_bf16.h>
#include <stdint.h>

typedef __bf16  bf16x8 __attribute__((ext_vector_type(8)));
typedef __bf16  bf16x4 __attribute__((ext_vector_type(4)));
typedef float   f32x4  __attribute__((ext_vector_type(4)));
typedef uint32_t u32x4 __attribute__((ext_vector_type(4)));

#define SLEN  2048
#define DHEAD 128
#define QBLK  64            // 4 waves x 16 q-rows
#define KVBLK 32
#define NQT   (SLEN / QBLK) // 32
#define THR2  11.5415603f   // 8 * log2(e): defer-max threshold in exp2 domain

__device__ __forceinline__ uint32_t cvt_pk(float lo, float hi2) {
    uint32_t u;
    asm("v_cvt_pk_bf16_f32 %0, %1, %2" : "=v"(u) : "v"(lo), "v"(hi2));
    return u;
}

__device__ __forceinline__ float exp2fast(float x) {
    return __builtin_amdgcn_exp2f(x);
}

__global__ __launch_bounds__(256, 3) void attn_fwd(
    const float* __restrict__ Q, const float* __restrict__ K,
    const float* __restrict__ V, float* __restrict__ O)
{
    const int bh = blockIdx.x;              // heads fastest
    const int qt = (NQT - 1) - blockIdx.y;  // LPT: longest first
    const int tid  = threadIdx.x;
    const int w    = tid >> 6;
    const int lane = tid & 63;
    const int r    = lane & 15;
    const int g    = lane >> 4;

    const size_t head_off = (size_t)bh * SLEN * DHEAD;
    const float* Qh = Q + head_off;
    const float* Kh = K + head_off;
    const float* Vh = V + head_off;
    float*       Oh = O + head_off;

    const int q0w = qt * QBLK + w * 16;     // wave's first q row

    __shared__ __bf16 K_sh [2][KVBLK * DHEAD];  // [32][256B], swz (row&15)<<4
    __shared__ __bf16 Vt_sh[2][DHEAD * 40];     // [128][80B], quad-xor swz

    // exp2-domain: fold log2(e) into the QK scale
    const float scale = 0.08838834764831845f * 1.4426950408889634f;

    // ---- Q fragments (B operand): col=q0w+r, k = kb*32 + g*8 + e ----
    bf16x8 qfrag[4];
    {
        const float4* qp = reinterpret_cast<const float4*>(
            Qh + (size_t)(q0w + r) * DHEAD + g * 8);
        #pragma unroll
        for (int kb = 0; kb < 4; ++kb) {
            float4 a = qp[kb*8 + 0];
            float4 b = qp[kb*8 + 1];
            a.x*=scale; a.y*=scale; a.z*=scale; a.w*=scale;
            b.x*=scale; b.y*=scale; b.z*=scale; b.w*=scale;
            bf16x8 f;
            f[0]=(__bf16)a.x; f[1]=(__bf16)a.y; f[2]=(__bf16)a.z; f[3]=(__bf16)a.w;
            f[4]=(__bf16)b.x; f[5]=(__bf16)b.y; f[6]=(__bf16)b.z; f[7]=(__bf16)b.w;
            qfrag[kb] = f;
        }
    }

    // staging regs
    float4 kreg[4], vreg[4];
    const int c4  = tid & 31;
    const int kvq = tid >> 5;        // 0..7: V kv-quad

    auto issue_loads = [&](int kv0) {
        #pragma unroll
        for (int it = 0; it < 4; ++it) {
            const int row = (it * 256 + tid) >> 5;
            kreg[it] = *reinterpret_cast<const float4*>(
                Kh + (size_t)(kv0 + row) * DHEAD + c4 * 4);
        }
        #pragma unroll
        for (int kr = 0; kr < 4; ++kr)
            vreg[kr] = *reinterpret_cast<const float4*>(
                Vh + (size_t)(kv0 + kvq * 4 + kr) * DHEAD + c4 * 4);
    };

    auto write_tiles = [&](int buf) {
        char* Kb  = reinterpret_cast<char*>(K_sh[buf]);
        char* Vtb = reinterpret_cast<char*>(Vt_sh[buf]);
        #pragma unroll
        for (int it = 0; it < 4; ++it) {
            const int row = (it * 256 + tid) >> 5;
            bf16x4 k4;
            k4[0]=(__bf16)kreg[it].x; k4[1]=(__bf16)kreg[it].y;
            k4[2]=(__bf16)kreg[it].z; k4[3]=(__bf16)kreg[it].w;
            *reinterpret_cast<bf16x4*>(
                Kb + row * 256 + ((c4 * 8) ^ ((row & 15) << 4))) = k4;
        }
        #pragma unroll
        for (int j = 0; j < 4; ++j) {
            const int d = c4 * 4 + j;
            bf16x4 v4;
            #pragma unroll
            for (int kr = 0; kr < 4; ++kr)
                v4[kr] = (__bf16)((&vreg[kr].x)[j]);
            *reinterpret_cast<bf16x4*>(
                Vtb + d * 80 + ((kvq ^ ((d >> 2) & 6)) * 8)) = v4;
        }
    };

    const f32x4 vzero = {0.f, 0.f, 0.f, 0.f};
    f32x4 acc_o[8];
    #pragma unroll
    for (int i = 0; i < 8; ++i) acc_o[i] = vzero;
    float m_run = -1e30f, l_run = 0.f;

    const int n_iter = 2 * qt + 2;           // tiles 0 .. n_iter-1 (even count)
    const int my_max = (q0w + 15) >> 5;      // wave's last live tile index

    // ---- QK of tile t from K buffer kb_buf into st[2] ----
    auto do_qk = [&](f32x4* st, int t, int kb_buf) {
        char* Kb = reinterpret_cast<char*>(K_sh[kb_buf]);
        const bool a1 = (t * KVBLK + 16 <= q0w + 15);
        __builtin_amdgcn_s_setprio(1);
        #pragma unroll
        for (int tt = 0; tt < 2; ++tt) {
            st[tt] = vzero;
            if (tt == 1 && !a1) break;
            const int row = tt * 16 + r;
            #pragma unroll
            for (int kb = 0; kb < 4; ++kb) {
                bf16x8 kf = *reinterpret_cast<const bf16x8*>(
                    Kb + row * 256 + ((kb*64 + g*16) ^ ((row & 15) << 4)));
                st[tt] = __builtin_amdgcn_mfma_f32_16x16x32_bf16(
                    kf, qfrag[kb], st[tt], 0, 0, 0);
            }
        }
        __builtin_amdgcn_s_setprio(0);
    };

    // ---- softmax + PV of tile t (scores in st, V in Vt buffer vt_buf) ----
    auto process = [&](f32x4* st, int t, int vt_buf) {
        const int kv0 = t * KVBLK;
        char* Vtb = reinterpret_cast<char*>(Vt_sh[vt_buf]);
        const bool alive1 = (kv0 + 16 <= q0w + 15);

        const int q = q0w + r;
        float pmax = -1e30f;
        #pragma unroll
        for (int tt = 0; tt < 2; ++tt) {
            if (tt == 1 && !alive1) break;
            if (kv0 + tt*16 + 15 > q0w) {
                #pragma unroll
                for (int j = 0; j < 4; ++j)
                    if (kv0 + tt*16 + 4*g + j > q) st[tt][j] = -1e30f;
            }
            #pragma unroll
            for (int j = 0; j < 4; ++j) pmax = fmaxf(pmax, st[tt][j]);
        }
        pmax = fmaxf(pmax, __shfl_xor(pmax, 16));
        pmax = fmaxf(pmax, __shfl_xor(pmax, 32));

        if (__any(pmax > m_run + THR2)) {        // rare (defer-max)
            const float m_new = fmaxf(m_run, pmax);
            const float corr  = exp2fast(m_run - m_new);
            l_run *= corr; m_run = m_new;
            #pragma unroll
            for (int reg = 0; reg < 4; ++reg) {
                const float cr = __shfl(corr, 4*g + reg);
                #pragma unroll
                for (int dt = 0; dt < 8; ++dt) acc_o[dt][reg] *= cr;
            }
        }

        float rowsum = 0.f;
        #pragma unroll
        for (int tt = 0; tt < 2; ++tt) {
            if (tt == 1 && !alive1) break;
            #pragma unroll
            for (int j = 0; j < 4; ++j) {
                const float p = exp2fast(st[tt][j] - m_run);
                st[tt][j] = p;
                rowsum += p;
            }
        }
        rowsum += __shfl_xor(rowsum, 16);
        rowsum += __shfl_xor(rowsum, 32);
        l_run += rowsum;

        // P redistribute to A-fragment (k = g*8 + e)
        const uint32_t p00 = cvt_pk(st[0][0], st[0][1]);
        const uint32_t p01 = cvt_pk(st[0][2], st[0][3]);
        const uint32_t p10 = alive1 ? cvt_pk(st[1][0], st[1][1]) : 0u;
        const uint32_t p11 = alive1 ? cvt_pk(st[1][2], st[1][3]) : 0u;
        const int sA = r + ((2 * (g & 1)) << 4);
        const int sB = r + ((2 * (g & 1) + 1) << 4);
        u32x4 words;
        {
            const uint32_t lo0 = (uint32_t)__shfl((int)p00, sA);
            const uint32_t hi0 = (uint32_t)__shfl((int)p10, sA);
            const uint32_t lo1 = (uint32_t)__shfl((int)p01, sA);
            const uint32_t hi1 = (uint32_t)__shfl((int)p11, sA);
            const uint32_t lo2 = (uint32_t)__shfl((int)p00, sB);
            const uint32_t hi2 = (uint32_t)__shfl((int)p10, sB);
            const uint32_t lo3 = (uint32_t)__shfl((int)p01, sB);
            const uint32_t hi3 = (uint32_t)__shfl((int)p11, sB);
            words[0] = (g & 2) ? hi0 : lo0;
            words[1] = (g & 2) ? hi1 : lo1;
            words[2] = (g & 2) ? hi2 : lo2;
            words[3] = (g & 2) ? hi3 : lo3;
        }
        const bf16x8 pa = __builtin_bit_cast(bf16x8, words);

        __builtin_amdgcn_s_setprio(1);
        #pragma unroll
        for (int dt = 0; dt < 8; ++dt) {
            const int d = dt * 16 + r;
            bf16x8 vf = *reinterpret_cast<const bf16x8*>(
                Vtb + d * 80 + (((2*g) ^ ((d >> 2) & 6)) * 8));
            acc_o[dt] = __builtin_amdgcn_mfma_f32_16x16x32_bf16(
                pa, vf, acc_o[dt], 0, 0, 0);
        }
        __builtin_amdgcn_s_setprio(0);
    };

    // ---- prologue: stage tiles 0 and 1, QK(0) ----
    issue_loads(0);
    write_tiles(0);
    __syncthreads();
    issue_loads(KVBLK);
    f32x4 stA[2] = {vzero, vzero};
    f32x4 stB[2] = {vzero, vzero};
    do_qk(stA, 0, 0);
    write_tiles(1);

    // ---- main loop, unrolled x2: static stA/stB rotation ----
    for (int i = 0; i < n_iter; i += 2) {
        // sub-iter A: process tile i (stA, Vt buf0); prefetch QK(i+1) -> stB
        __syncthreads();                         // buf1 (tile i+1) ready
        if (i + 2 < n_iter) issue_loads((i + 2) * KVBLK);
        if (i + 1 <= my_max) do_qk(stB, i + 1, 1);
        if (i     <= my_max) process(stA, i, 0);
        __syncthreads();                         // PV reads of buf0 done
        if (i + 2 < n_iter) write_tiles(0);      // tile i+2 -> buf0

        // sub-iter B: process tile i+1 (stB, Vt buf1); prefetch QK(i+2) -> stA
        __syncthreads();                         // buf0 (tile i+2) ready
        if (i + 3 < n_iter) issue_loads((i + 3) * KVBLK);
        if (i + 2 <= my_max) do_qk(stA, i + 2, 0);
        if (i + 1 <= my_max) process(stB, i + 1, 1);
        __syncthreads();                         // PV reads of buf1 done
        if (i + 3 < n_iter) write_tiles(1);      // tile i+3 -> buf1
    }

    // ---- epilogue: O[q0w + 4g + reg][dt*16 + r] = acc / l ----
    const float inv = 1.0f / l_run;
    #pragma unroll
    for (int reg = 0; reg < 4; ++reg) {
        const float iv = __shfl(inv, 4*g + reg);
        float* orow = Oh + (size_t)(q0w + 4*g + reg) * DHEAD + r;
        #pragma unroll
        for (int dt = 0; dt < 8; ++dt)
            orow[dt * 16] = acc_o[dt][reg] * iv;
    }
}

extern "C" void kernel_launch(void* const* d_in, const int* in_sizes, int n_in,
                              void* d_out, int out_size, void* d_ws, size_t ws_size,
                              hipStream_t stream) {
    const float* Q = (const float*)d_in[0];
    const float* K = (const float*)d_in[1];
    const float* V = (const float*)d_in[2];
    float* O = (float*)d_out;
    dim3 grid(32 /* B*H */, NQT);
    attn_fwd<<<grid, 256, 0, stream>>>(Q, K, V, O);
}